// Round 12
// baseline (158.849 us; speedup 1.0000x reference)
//
#include <hip/hip_runtime.h>

// SMD solar-desal system simulation: T=4096 steps, B=2048 batch.
// Per-step update is AFFINE in the reduced state (T2,T3,T4,T6,T8); T1==T4.
//   Phase A: 512-thread blocks; tid<256 composes basis cols 0-2, tid>=256
//            cols 3-4 + offset for the SAME 256 batch columns. Both halves
//            read identical input addresses -> 2nd read is L1-hit (fixes
//            R10's doubled-HBM failure). 15 state floats/thread + LB(512,8)
//            targets <=64 VGPR -> 8 waves/SIMD (2x TLP vs R11's 4).
//   Phase B: per batch, block-level Hillis-Steele scan over chunk maps
//            (unpacks the split map layout; validated in R10, absmax 512)
//   Phase C: per (chunk,batch-pair) replay chunk, emit 7 output histories
// NCHUNK=128 (256 regressed, R9). maps [b][c][32]: floats 0-14 = cols 0-2,
// 16-30 = cols 3,4,offset. states [c][b][8]. Intermediates REGULAR cached
// (NT cost +19us, R7). NT only for the out stream.

#define T_STEPS 4096
#define BATCH   2048
#define NCHUNK  128
#define CLEN    32   // T_STEPS / NCHUNK

typedef float f2 __attribute__((ext_vector_type(2)));
typedef float f4 __attribute__((ext_vector_type(4)));

struct StepScal {
    float v, uata, m1, m2, m12u, cpLm1, e16, e245, cst2, kq, rdt;
};

// exp(theta) for this workload: theta in (0, ~0.007) -> 4-term Taylor is
// sub-ULP exact (theta^4/24 < 1e-10). Guarded fallback keeps generality.
__device__ __forceinline__ float exp_small(float x)
{
    if (__builtin_expect(fabsf(x) < 0.008f, 1)) {
        float x2 = x * x;
        return 1.0f + x + x2 * 0.5f + x2 * x * (1.0f / 6.0f);
    }
    return expf(x);
}

__device__ __forceinline__ StepScal make_scal(
    float v, float ii, float ta, float f1, float f2_, float f3,
    float kq, float rdt)
{
    const float UA_CP = 100.0f / 4186.0f;
    StepScal sc;
    sc.v  = v;
    sc.m1 = f1 * (1.0f/60.0f);                 // F1*rho/c1 == F1*rho/60000
    sc.m2 = (1.0f - v) * f2_ * (1.0f/60.0f);
    sc.m12u = sc.m1 + sc.m2 + UA_CP;           // folded tank diagonal
    sc.uata = UA_CP * ta;                      // folded ambient leak term
    sc.cpLm1 = 41.86f * sc.m1;                 // (c_p/L_eq)*m1
    float a_ = f2_ * (4186.0f/60.0f);          // m3*c_p
    float b_ = f3 * (1025.0f*4000.0f/60000.0f);// m4*c_p_sw
    float inv_ab = 1.0f / (a_ * b_);
    float rc    = a_ * a_ * inv_ab;            // m3*c_p/(m4*c_p_sw)
    float theta = 10.0f * (b_ - a_) * inv_ab;  // aA=alpha_he*A_he=10
    float e = exp_small(theta);
    float eta1 = (1.0f - e) / (1.1f - rc * e);
    sc.e16  = 1.6f  * eta1;
    sc.e245 = 0.45f * rc;                      // eta2 = rc
    sc.cst2 = 0.5f * ii + 0.04f * ta;          // beta*I + (H/L_eq)*Ta
    sc.kq = kq;
    sc.rdt = rdt;
    return sc;
}

// One simulation step on reduced state s = (T2,T3,T4,T6,T8), T1==T4.
// OFF=true: full affine step; OFF=false: linear part only (basis columns).
template<bool OFF, bool EMIT>
__device__ __forceinline__ void smd_step(float s[5], const StepScal& sc, float* o)
{
    float t2 = s[0], t3 = s[1], t4 = s[2], t6 = s[3], t8 = s[4];

    float lin = -0.04f * (0.5f * (t4 + t2)) - sc.cpLm1 * (t2 - t4);
    if (OFF) lin += sc.cst2;
    float t2n = fmaf(sc.kq, lin, t2);

    float c3 = fmaf(sc.m2, t4, sc.m1 * t2n) - sc.m12u * t3;
    float c4 = fmaf(sc.m2, t6, sc.m1 * t3 ) - sc.m12u * t4;
    if (OFF) { c3 += sc.uata; c4 += sc.uata; }
    float t3n = fmaf(sc.rdt, c3, t3);
    float t4n = fmaf(sc.rdt, c4, t4);

    float t5 = fmaf(sc.v, t6 - t3n, t3n);
    float t7 = OFF ? (t8 - 4.0f) : t8;
    float t6n = fmaf(-sc.e16, t5 - t7, t5);
    float t8n = fmaf(sc.e245, t5 - t6n, t7);

    s[0] = t2n; s[1] = t3n; s[2] = t4n; s[3] = t6n; s[4] = t8n;
    if (EMIT) {
        o[0] = t2n; o[1] = t3n; o[2] = t4n; o[3] = t5;
        o[4] = t6n; o[5] = t7;  o[6] = t8n;
    }
}

// 512 threads: lower half composes basis cols 0-2, upper half cols 3-4 +
// offset, for the same 256 batch columns (shared L1 for input loads).
__global__ __launch_bounds__(512, 8) void phaseA(
    const float* __restrict__ V, const float* __restrict__ I,
    const float* __restrict__ Ta, const float* __restrict__ F1,
    const float* __restrict__ F2, const float* __restrict__ F3,
    const int* __restrict__ dtp, float* __restrict__ maps)
{
    const int tid  = threadIdx.x;
    const int half = tid >> 8;              // wave-uniform
    const int b = blockIdx.x * 256 + (tid & 255);
    const int c = blockIdx.y;
    const float dtf = (float)dtp[0];
    const float kq  = dtf * (1.0f / 2.093e9f);   // dt/(A_sf*rho*c_p)
    const float rdt = dtf * 1e-4f;               // dt/(rho*TV)

    float s[3][5];
#pragma unroll
    for (int j = 0; j < 3; ++j)
#pragma unroll
        for (int i = 0; i < 5; ++i) s[j][i] = 0.0f;

    int idx = c * CLEN * BATCH + b;
    if (half == 0) {
        s[0][0] = 1.0f; s[1][1] = 1.0f; s[2][2] = 1.0f;
#pragma unroll 2
        for (int k = 0; k < CLEN; ++k, idx += BATCH) {
            StepScal sc = make_scal(V[idx], I[idx], Ta[idx], F1[idx], F2[idx], F3[idx], kq, rdt);
            smd_step<false, false>(s[0], sc, nullptr);
            smd_step<false, false>(s[1], sc, nullptr);
            smd_step<false, false>(s[2], sc, nullptr);
        }
    } else {
        s[0][3] = 1.0f; s[1][4] = 1.0f;     // s[2] = offset column (zero)
#pragma unroll 2
        for (int k = 0; k < CLEN; ++k, idx += BATCH) {
            StepScal sc = make_scal(V[idx], I[idx], Ta[idx], F1[idx], F2[idx], F3[idx], kq, rdt);
            smd_step<false, false>(s[0], sc, nullptr);
            smd_step<false, false>(s[1], sc, nullptr);
            smd_step<true,  false>(s[2], sc, nullptr);
        }
    }

    float tmp[16];
#pragma unroll
    for (int j = 0; j < 3; ++j)
#pragma unroll
        for (int i = 0; i < 5; ++i) tmp[j * 5 + i] = s[j][i];
    tmp[15] = 0.0f;
    // maps layout [b][c][32], half h owns floats [16h, 16h+16)
    f4* mp = (f4*)(maps + ((size_t)b * NCHUNK + c) * 32 + half * 16);
#pragma unroll
    for (int k = 0; k < 4; ++k) mp[k] = ((const f4*)tmp)[k];
}

// One block (NCHUNK thr) per batch element; thread c = chunk c.
// Hillis-Steele inclusive scan of affine maps; exclusive prefix -> start state.
__global__ __launch_bounds__(NCHUNK) void phaseB(
    const float* __restrict__ maps, float* __restrict__ states)
{
    __shared__ float lds[NCHUNK * 33];
    const int b = blockIdx.x;
    const int c = threadIdx.x;

    float raw[32];
    const f4* mp = (const f4*)(maps + ((size_t)b * NCHUNK + c) * 32);
#pragma unroll
    for (int k = 0; k < 8; ++k) ((f4*)raw)[k] = mp[k];
    // unpack split layout: cols 0-2 at raw[0..14]; col3 raw[16..20];
    // col4 raw[21..25]; offset raw[26..30] -> m[j*5+i], m[25+i]
    float m[30];
#pragma unroll
    for (int k = 0; k < 15; ++k) m[k] = raw[k];
#pragma unroll
    for (int k = 0; k < 15; ++k) m[15 + k] = raw[16 + k];

#pragma unroll
    for (int d = 1; d < NCHUNK; d <<= 1) {
#pragma unroll
        for (int k = 0; k < 30; ++k) lds[c * 33 + k] = m[k];
        __syncthreads();
        float o[30];
        const bool act = (c >= d);
        if (act) {
#pragma unroll
            for (int k = 0; k < 30; ++k) o[k] = lds[(c - d) * 33 + k];
        }
        __syncthreads();
        if (act) {
            // compose: result = mine ∘ other (other applied first)
            float nm[30];
#pragma unroll
            for (int j = 0; j < 5; ++j)
#pragma unroll
                for (int i = 0; i < 5; ++i) {
                    float acc = m[0 * 5 + i] * o[j * 5 + 0];
#pragma unroll
                    for (int k = 1; k < 5; ++k)
                        acc = fmaf(m[k * 5 + i], o[j * 5 + k], acc);
                    nm[j * 5 + i] = acc;
                }
#pragma unroll
            for (int i = 0; i < 5; ++i) {
                float acc = m[25 + i];
#pragma unroll
                for (int k = 0; k < 5; ++k)
                    acc = fmaf(m[k * 5 + i], o[25 + k], acc);
                nm[25 + i] = acc;
            }
#pragma unroll
            for (int k = 0; k < 30; ++k) m[k] = nm[k];
        }
    }

    // exclusive prefix -> chunk-start state
#pragma unroll
    for (int k = 0; k < 30; ++k) lds[c * 33 + k] = m[k];
    __syncthreads();

    const float s0[5] = {60.0f, 60.0f, 50.0f, 25.0f, 60.0f};
    float st[8];
#pragma unroll
    for (int i = 0; i < 5; ++i) st[i] = s0[i];
    st[5] = 0.0f; st[6] = 0.0f; st[7] = 0.0f;
    if (c > 0) {
        const float* pm = &lds[(c - 1) * 33];
#pragma unroll
        for (int i = 0; i < 5; ++i) {
            float acc = pm[25 + i];
#pragma unroll
            for (int j = 0; j < 5; ++j)
                acc = fmaf(pm[j * 5 + i], s0[j], acc);
            st[i] = acc;
        }
    }
    // states layout [c][b][8]; regular cached stores (phase C re-reads these).
    f4* op = (f4*)(states + ((size_t)c * BATCH + b) * 8);
    op[0] = ((const f4*)st)[0];
    op[1] = ((const f4*)st)[1];
}

// Two adjacent batch columns per thread: all global traffic is dwordx2.
// (Safe here: only 5 live state floats per column.)
__global__ __launch_bounds__(256, 4) void phaseC(
    const float* __restrict__ V, const float* __restrict__ I,
    const float* __restrict__ Ta, const float* __restrict__ F1,
    const float* __restrict__ F2, const float* __restrict__ F3,
    const int* __restrict__ dtp, const float* __restrict__ states,
    float* __restrict__ out)
{
    const int pair = blockIdx.x * blockDim.x + threadIdx.x;
    const int b = pair * 2;
    const int c = blockIdx.y;
    const float dtf = (float)dtp[0];
    const float kq  = dtf * (1.0f / 2.093e9f);
    const float rdt = dtf * 1e-4f;

    // states for b and b+1 are 64 contiguous bytes: 4x f4.
    const f4* sp4 = (const f4*)(states + ((size_t)c * BATCH + b) * 8);
    f4 q0 = sp4[0], q1 = sp4[1], q2 = sp4[2], q3 = sp4[3];
    float s0v[5] = {q0.x, q0.y, q0.z, q0.w, q1.x};
    float s1v[5] = {q2.x, q2.y, q2.z, q2.w, q3.x};

    int idx = c * CLEN * BATCH + b;
#pragma unroll 4
    for (int k = 0; k < CLEN; ++k, idx += BATCH) {
        f2 v2  = *(const f2*)&V[idx];
        f2 i2  = *(const f2*)&I[idx];
        f2 ta2 = *(const f2*)&Ta[idx];
        f2 f12 = *(const f2*)&F1[idx];
        f2 f22 = *(const f2*)&F2[idx];
        f2 f32 = *(const f2*)&F3[idx];
        StepScal sca = make_scal(v2.x, i2.x, ta2.x, f12.x, f22.x, f32.x, kq, rdt);
        StepScal scb = make_scal(v2.y, i2.y, ta2.y, f12.y, f22.y, f32.y, kq, rdt);
        float oa[7], ob[7];
        smd_step<true, true>(s0v, sca, oa);
        smd_step<true, true>(s1v, scb, ob);
#pragma unroll
        for (int q = 0; q < 7; ++q) {
            f2 w; w.x = oa[q]; w.y = ob[q];
            __builtin_nontemporal_store(w, (f2*)&out[q * (T_STEPS * BATCH) + idx]);
        }
    }
}

// Fallback if d_ws is too small: plain serial per batch.
__global__ __launch_bounds__(256) void serialK(
    const float* __restrict__ V, const float* __restrict__ I,
    const float* __restrict__ Ta, const float* __restrict__ F1,
    const float* __restrict__ F2, const float* __restrict__ F3,
    const int* __restrict__ dtp, float* __restrict__ out)
{
    const int b = blockIdx.x * blockDim.x + threadIdx.x;
    const float dtf = (float)dtp[0];
    const float kq  = dtf * (1.0f / 2.093e9f);
    const float rdt = dtf * 1e-4f;
    float s[5] = {60.0f, 60.0f, 50.0f, 25.0f, 60.0f};
    int idx = b;
    for (int t = 0; t < T_STEPS; ++t, idx += BATCH) {
        StepScal sc = make_scal(V[idx], I[idx], Ta[idx], F1[idx], F2[idx], F3[idx], kq, rdt);
        float o[7];
        smd_step<true, true>(s, sc, o);
#pragma unroll
        for (int q = 0; q < 7; ++q)
            __builtin_nontemporal_store(o[q], &out[q * (T_STEPS * BATCH) + idx]);
    }
}

extern "C" void kernel_launch(void* const* d_in, const int* in_sizes, int n_in,
                              void* d_out, int out_size, void* d_ws, size_t ws_size,
                              hipStream_t stream)
{
    const float* V  = (const float*)d_in[0];
    const float* I  = (const float*)d_in[1];
    const float* Ta = (const float*)d_in[2];
    const float* F1 = (const float*)d_in[3];
    const float* F2 = (const float*)d_in[4];
    const float* F3 = (const float*)d_in[5];
    const int*  dtp = (const int*)d_in[6];
    float* out = (float*)d_out;

    const size_t need = ((size_t)NCHUNK * BATCH * 32 + (size_t)NCHUNK * BATCH * 8) * sizeof(float);
    if (need <= ws_size) {
        float* maps   = (float*)d_ws;                           // BATCH*NCHUNK*32 floats
        float* states = maps + (size_t)BATCH * NCHUNK * 32;     // NCHUNK*BATCH*8 floats
        hipLaunchKernelGGL(phaseA, dim3(BATCH / 256, NCHUNK), dim3(512), 0, stream,
                           V, I, Ta, F1, F2, F3, dtp, maps);
        hipLaunchKernelGGL(phaseB, dim3(BATCH), dim3(NCHUNK), 0, stream,
                           maps, states);
        hipLaunchKernelGGL(phaseC, dim3(BATCH / 512, NCHUNK), dim3(256), 0, stream,
                           V, I, Ta, F1, F2, F3, dtp, states, out);
    } else {
        hipLaunchKernelGGL(serialK, dim3(BATCH / 256), dim3(256), 0, stream,
                           V, I, Ta, F1, F2, F3, dtp, out);
    }
}

// Round 13
// 142.824 us; speedup vs baseline: 1.1122x; 1.1122x over previous
//
#include <hip/hip_runtime.h>

// SMD solar-desal system simulation: T=4096 steps, B=2048 batch.
// Per-step update is AFFINE in the reduced state (T2,T3,T4,T6,T8); T1==T4.
//   Phase A: per (chunk,batch) compose the chunk's 5x5+5 affine map.
//            A is LATENCY-bound (17% VALU, 2.3 TB/s). Inputs are LDS-staged
//            in 4-step groups: 6 coalesced f4 loads per wave (1 KB/instr)
//            replace 24 scalar loads -> 4x fewer VMEM instrs, loads issued
//            before the barrier overlap other waves' compute.
//            (Column splits fail: R10/R12. Batch pairing spills: R6.)
//   Phase B: per batch, block-level Hillis-Steele scan over chunk maps
//   Phase C: per (chunk,batch-pair) replay chunk, emit 7 output histories
//            (reads are L3-warm from A's pass; writes NT at ~floor)
// NCHUNK=128 (256 regressed, R9). maps [b][c][32] contiguous 0..29.
// states [c][b][8]. Intermediates REGULAR cached (NT cost +19us, R7).

#define T_STEPS 4096
#define BATCH   2048
#define NCHUNK  128
#define CLEN    32   // T_STEPS / NCHUNK
#define GSTEP   4    // steps staged per LDS group (24 KB -> 4 blocks/CU fit 96KB)

typedef float f2 __attribute__((ext_vector_type(2)));
typedef float f4 __attribute__((ext_vector_type(4)));

struct StepScal {
    float v, uata, m1, m2, m12u, cpLm1, e16, e245, cst2, kq, rdt;
};

// exp(theta) for this workload: theta in (0, ~0.007) -> 4-term Taylor is
// sub-ULP exact (theta^4/24 < 1e-10). Guarded fallback keeps generality.
__device__ __forceinline__ float exp_small(float x)
{
    if (__builtin_expect(fabsf(x) < 0.008f, 1)) {
        float x2 = x * x;
        return 1.0f + x + x2 * 0.5f + x2 * x * (1.0f / 6.0f);
    }
    return expf(x);
}

__device__ __forceinline__ StepScal make_scal(
    float v, float ii, float ta, float f1, float f2_, float f3,
    float kq, float rdt)
{
    const float UA_CP = 100.0f / 4186.0f;
    StepScal sc;
    sc.v  = v;
    sc.m1 = f1 * (1.0f/60.0f);                 // F1*rho/c1 == F1*rho/60000
    sc.m2 = (1.0f - v) * f2_ * (1.0f/60.0f);
    sc.m12u = sc.m1 + sc.m2 + UA_CP;           // folded tank diagonal
    sc.uata = UA_CP * ta;                      // folded ambient leak term
    sc.cpLm1 = 41.86f * sc.m1;                 // (c_p/L_eq)*m1
    float a_ = f2_ * (4186.0f/60.0f);          // m3*c_p
    float b_ = f3 * (1025.0f*4000.0f/60000.0f);// m4*c_p_sw
    float inv_ab = 1.0f / (a_ * b_);
    float rc    = a_ * a_ * inv_ab;            // m3*c_p/(m4*c_p_sw)
    float theta = 10.0f * (b_ - a_) * inv_ab;  // aA=alpha_he*A_he=10
    float e = exp_small(theta);
    float eta1 = (1.0f - e) / (1.1f - rc * e);
    sc.e16  = 1.6f  * eta1;
    sc.e245 = 0.45f * rc;                      // eta2 = rc
    sc.cst2 = 0.5f * ii + 0.04f * ta;          // beta*I + (H/L_eq)*Ta
    sc.kq = kq;
    sc.rdt = rdt;
    return sc;
}

// One simulation step on reduced state s = (T2,T3,T4,T6,T8), T1==T4.
// OFF=true: full affine step; OFF=false: linear part only (basis columns).
template<bool OFF, bool EMIT>
__device__ __forceinline__ void smd_step(float s[5], const StepScal& sc, float* o)
{
    float t2 = s[0], t3 = s[1], t4 = s[2], t6 = s[3], t8 = s[4];

    float lin = -0.04f * (0.5f * (t4 + t2)) - sc.cpLm1 * (t2 - t4);
    if (OFF) lin += sc.cst2;
    float t2n = fmaf(sc.kq, lin, t2);

    float c3 = fmaf(sc.m2, t4, sc.m1 * t2n) - sc.m12u * t3;
    float c4 = fmaf(sc.m2, t6, sc.m1 * t3 ) - sc.m12u * t4;
    if (OFF) { c3 += sc.uata; c4 += sc.uata; }
    float t3n = fmaf(sc.rdt, c3, t3);
    float t4n = fmaf(sc.rdt, c4, t4);

    float t5 = fmaf(sc.v, t6 - t3n, t3n);
    float t7 = OFF ? (t8 - 4.0f) : t8;
    float t6n = fmaf(-sc.e16, t5 - t7, t5);
    float t8n = fmaf(sc.e245, t5 - t6n, t7);

    s[0] = t2n; s[1] = t3n; s[2] = t4n; s[3] = t6n; s[4] = t8n;
    if (EMIT) {
        o[0] = t2n; o[1] = t3n; o[2] = t4n; o[3] = t5;
        o[4] = t6n; o[5] = t7;  o[6] = t8n;
    }
}

// LDS-staged: per group, wave w stages step (k0+w) of all 6 arrays with
// f4 loads; compute reads LDS (lane=col -> conflict-free).
__global__ __launch_bounds__(256) void phaseA(
    const float* __restrict__ V, const float* __restrict__ I,
    const float* __restrict__ Ta, const float* __restrict__ F1,
    const float* __restrict__ F2, const float* __restrict__ F3,
    const int* __restrict__ dtp, float* __restrict__ maps)
{
    __shared__ float lds[6 * GSTEP * 256];   // 24 KB
    const int t  = threadIdx.x;
    const int b0 = blockIdx.x * 256;
    const int b  = b0 + t;
    const int c  = blockIdx.y;
    const float dtf = (float)dtp[0];
    const float kq  = dtf * (1.0f / 2.093e9f);   // dt/(A_sf*rho*c_p)
    const float rdt = dtf * 1e-4f;               // dt/(rho*TV)

    const int i4 = t >> 6;          // step-within-group this thread stages
    const int m4 = (t & 63) << 2;   // col offset it stages (f4)

    float s[6][5];
#pragma unroll
    for (int j = 0; j < 6; ++j)
#pragma unroll
        for (int i = 0; i < 5; ++i) s[j][i] = (i == j) ? 1.0f : 0.0f;

    const int chunk0 = c * CLEN * BATCH + b0;
    for (int g = 0; g < CLEN / GSTEP; ++g) {
        const int gbase = chunk0 + (g * GSTEP + i4) * BATCH + m4;
        f4 va = *(const f4*)&V [gbase];
        f4 vb = *(const f4*)&I [gbase];
        f4 vc = *(const f4*)&Ta[gbase];
        f4 vd = *(const f4*)&F1[gbase];
        f4 ve = *(const f4*)&F2[gbase];
        f4 vf = *(const f4*)&F3[gbase];
        __syncthreads();   // previous group's compute done before overwrite
        *(f4*)&lds[(0 * GSTEP + i4) * 256 + m4] = va;
        *(f4*)&lds[(1 * GSTEP + i4) * 256 + m4] = vb;
        *(f4*)&lds[(2 * GSTEP + i4) * 256 + m4] = vc;
        *(f4*)&lds[(3 * GSTEP + i4) * 256 + m4] = vd;
        *(f4*)&lds[(4 * GSTEP + i4) * 256 + m4] = ve;
        *(f4*)&lds[(5 * GSTEP + i4) * 256 + m4] = vf;
        __syncthreads();
#pragma unroll
        for (int k = 0; k < GSTEP; ++k) {
            StepScal sc = make_scal(lds[(0 * GSTEP + k) * 256 + t],
                                    lds[(1 * GSTEP + k) * 256 + t],
                                    lds[(2 * GSTEP + k) * 256 + t],
                                    lds[(3 * GSTEP + k) * 256 + t],
                                    lds[(4 * GSTEP + k) * 256 + t],
                                    lds[(5 * GSTEP + k) * 256 + t], kq, rdt);
#pragma unroll
            for (int j = 0; j < 5; ++j) smd_step<false, false>(s[j], sc, nullptr);
            smd_step<true, false>(s[5], sc, nullptr);
        }
    }

    float tmp[32];
#pragma unroll
    for (int j = 0; j < 6; ++j)
#pragma unroll
        for (int i = 0; i < 5; ++i) tmp[j * 5 + i] = s[j][i];
    tmp[30] = 0.0f; tmp[31] = 0.0f;
    // maps layout [b][c][32] contiguous; regular cached stores.
    f4* mp = (f4*)(maps + ((size_t)b * NCHUNK + c) * 32);
#pragma unroll
    for (int k = 0; k < 8; ++k) mp[k] = ((const f4*)tmp)[k];
}

// One block (NCHUNK thr) per batch element; thread c = chunk c.
// Hillis-Steele inclusive scan of affine maps; exclusive prefix -> start state.
__global__ __launch_bounds__(NCHUNK) void phaseB(
    const float* __restrict__ maps, float* __restrict__ states)
{
    __shared__ float lds[NCHUNK * 33];
    const int b = blockIdx.x;
    const int c = threadIdx.x;

    float tmp[32];
    const f4* mp = (const f4*)(maps + ((size_t)b * NCHUNK + c) * 32);
#pragma unroll
    for (int k = 0; k < 8; ++k) ((f4*)tmp)[k] = mp[k];
    float m[30];
#pragma unroll
    for (int k = 0; k < 30; ++k) m[k] = tmp[k];

#pragma unroll
    for (int d = 1; d < NCHUNK; d <<= 1) {
#pragma unroll
        for (int k = 0; k < 30; ++k) lds[c * 33 + k] = m[k];
        __syncthreads();
        float o[30];
        const bool act = (c >= d);
        if (act) {
#pragma unroll
            for (int k = 0; k < 30; ++k) o[k] = lds[(c - d) * 33 + k];
        }
        __syncthreads();
        if (act) {
            // compose: result = mine ∘ other (other applied first)
            float nm[30];
#pragma unroll
            for (int j = 0; j < 5; ++j)
#pragma unroll
                for (int i = 0; i < 5; ++i) {
                    float acc = m[0 * 5 + i] * o[j * 5 + 0];
#pragma unroll
                    for (int k = 1; k < 5; ++k)
                        acc = fmaf(m[k * 5 + i], o[j * 5 + k], acc);
                    nm[j * 5 + i] = acc;
                }
#pragma unroll
            for (int i = 0; i < 5; ++i) {
                float acc = m[25 + i];
#pragma unroll
                for (int k = 0; k < 5; ++k)
                    acc = fmaf(m[k * 5 + i], o[25 + k], acc);
                nm[25 + i] = acc;
            }
#pragma unroll
            for (int k = 0; k < 30; ++k) m[k] = nm[k];
        }
    }

    // exclusive prefix -> chunk-start state
#pragma unroll
    for (int k = 0; k < 30; ++k) lds[c * 33 + k] = m[k];
    __syncthreads();

    const float s0[5] = {60.0f, 60.0f, 50.0f, 25.0f, 60.0f};
    float st[8];
#pragma unroll
    for (int i = 0; i < 5; ++i) st[i] = s0[i];
    st[5] = 0.0f; st[6] = 0.0f; st[7] = 0.0f;
    if (c > 0) {
        const float* pm = &lds[(c - 1) * 33];
#pragma unroll
        for (int i = 0; i < 5; ++i) {
            float acc = pm[25 + i];
#pragma unroll
            for (int j = 0; j < 5; ++j)
                acc = fmaf(pm[j * 5 + i], s0[j], acc);
            st[i] = acc;
        }
    }
    // states layout [c][b][8]; regular cached stores (phase C re-reads these).
    f4* op = (f4*)(states + ((size_t)c * BATCH + b) * 8);
    op[0] = ((const f4*)st)[0];
    op[1] = ((const f4*)st)[1];
}

// Two adjacent batch columns per thread: all global traffic is dwordx2.
// (Safe here: only 5 live state floats per column.)
__global__ __launch_bounds__(256, 4) void phaseC(
    const float* __restrict__ V, const float* __restrict__ I,
    const float* __restrict__ Ta, const float* __restrict__ F1,
    const float* __restrict__ F2, const float* __restrict__ F3,
    const int* __restrict__ dtp, const float* __restrict__ states,
    float* __restrict__ out)
{
    const int pair = blockIdx.x * blockDim.x + threadIdx.x;
    const int b = pair * 2;
    const int c = blockIdx.y;
    const float dtf = (float)dtp[0];
    const float kq  = dtf * (1.0f / 2.093e9f);
    const float rdt = dtf * 1e-4f;

    // states for b and b+1 are 64 contiguous bytes: 4x f4.
    const f4* sp4 = (const f4*)(states + ((size_t)c * BATCH + b) * 8);
    f4 q0 = sp4[0], q1 = sp4[1], q2 = sp4[2], q3 = sp4[3];
    float s0v[5] = {q0.x, q0.y, q0.z, q0.w, q1.x};
    float s1v[5] = {q2.x, q2.y, q2.z, q2.w, q3.x};

    int idx = c * CLEN * BATCH + b;
#pragma unroll 4
    for (int k = 0; k < CLEN; ++k, idx += BATCH) {
        f2 v2  = *(const f2*)&V[idx];
        f2 i2  = *(const f2*)&I[idx];
        f2 ta2 = *(const f2*)&Ta[idx];
        f2 f12 = *(const f2*)&F1[idx];
        f2 f22 = *(const f2*)&F2[idx];
        f2 f32 = *(const f2*)&F3[idx];
        StepScal sca = make_scal(v2.x, i2.x, ta2.x, f12.x, f22.x, f32.x, kq, rdt);
        StepScal scb = make_scal(v2.y, i2.y, ta2.y, f12.y, f22.y, f32.y, kq, rdt);
        float oa[7], ob[7];
        smd_step<true, true>(s0v, sca, oa);
        smd_step<true, true>(s1v, scb, ob);
#pragma unroll
        for (int q = 0; q < 7; ++q) {
            f2 w; w.x = oa[q]; w.y = ob[q];
            __builtin_nontemporal_store(w, (f2*)&out[q * (T_STEPS * BATCH) + idx]);
        }
    }
}

// Fallback if d_ws is too small: plain serial per batch.
__global__ __launch_bounds__(256) void serialK(
    const float* __restrict__ V, const float* __restrict__ I,
    const float* __restrict__ Ta, const float* __restrict__ F1,
    const float* __restrict__ F2, const float* __restrict__ F3,
    const int* __restrict__ dtp, float* __restrict__ out)
{
    const int b = blockIdx.x * blockDim.x + threadIdx.x;
    const float dtf = (float)dtp[0];
    const float kq  = dtf * (1.0f / 2.093e9f);
    const float rdt = dtf * 1e-4f;
    float s[5] = {60.0f, 60.0f, 50.0f, 25.0f, 60.0f};
    int idx = b;
    for (int t = 0; t < T_STEPS; ++t, idx += BATCH) {
        StepScal sc = make_scal(V[idx], I[idx], Ta[idx], F1[idx], F2[idx], F3[idx], kq, rdt);
        float o[7];
        smd_step<true, true>(s, sc, o);
#pragma unroll
        for (int q = 0; q < 7; ++q)
            __builtin_nontemporal_store(o[q], &out[q * (T_STEPS * BATCH) + idx]);
    }
}

extern "C" void kernel_launch(void* const* d_in, const int* in_sizes, int n_in,
                              void* d_out, int out_size, void* d_ws, size_t ws_size,
                              hipStream_t stream)
{
    const float* V  = (const float*)d_in[0];
    const float* I  = (const float*)d_in[1];
    const float* Ta = (const float*)d_in[2];
    const float* F1 = (const float*)d_in[3];
    const float* F2 = (const float*)d_in[4];
    const float* F3 = (const float*)d_in[5];
    const int*  dtp = (const int*)d_in[6];
    float* out = (float*)d_out;

    const size_t need = ((size_t)NCHUNK * BATCH * 32 + (size_t)NCHUNK * BATCH * 8) * sizeof(float);
    if (need <= ws_size) {
        float* maps   = (float*)d_ws;                           // BATCH*NCHUNK*32 floats
        float* states = maps + (size_t)BATCH * NCHUNK * 32;     // NCHUNK*BATCH*8 floats
        hipLaunchKernelGGL(phaseA, dim3(BATCH / 256, NCHUNK), dim3(256), 0, stream,
                           V, I, Ta, F1, F2, F3, dtp, maps);
        hipLaunchKernelGGL(phaseB, dim3(BATCH), dim3(NCHUNK), 0, stream,
                           maps, states);
        hipLaunchKernelGGL(phaseC, dim3(BATCH / 512, NCHUNK), dim3(256), 0, stream,
                           V, I, Ta, F1, F2, F3, dtp, states, out);
    } else {
        hipLaunchKernelGGL(serialK, dim3(BATCH / 256), dim3(256), 0, stream,
                           V, I, Ta, F1, F2, F3, dtp, out);
    }
}

// Round 14
// 137.074 us; speedup vs baseline: 1.1589x; 1.0419x over previous
//
#include <hip/hip_runtime.h>

// SMD solar-desal system simulation: T=4096 steps, B=2048 batch.
// Per-step update is AFFINE in the reduced state (T2,T3,T4,T6,T8); T1==T4.
//   Phase A: per (chunk,batch) compose the chunk's 5x5+5 affine map.
//            LDS-staged in 4-step groups with T14 async-STAGE split:
//            group g+1's global loads are issued BEFORE compute(g), so the
//            vmcnt wait (at next ds_write) lands after ~1064cy of compute
//            > ~900cy HBM latency -> latency fully hidden. (R13 issued
//            loads right before the consuming barrier: latency exposed.)
//            (Column splits fail: R10/R12. Batch pairing spills: R6.)
//   Phase B: per batch, block-level Hillis-Steele scan over chunk maps
//   Phase C: per (chunk,batch-pair) replay chunk, emit 7 output histories
// NCHUNK=128 (256 regressed, R9). maps [b][c][32] contiguous 0..29.
// states [c][b][8]. Intermediates REGULAR cached (NT cost +19us, R7).
// NT only for the final out stream.

#define T_STEPS 4096
#define BATCH   2048
#define NCHUNK  128
#define CLEN    32   // T_STEPS / NCHUNK
#define GSTEP   4    // steps staged per LDS group (24 KB -> 4 blocks/CU)

typedef float f2 __attribute__((ext_vector_type(2)));
typedef float f4 __attribute__((ext_vector_type(4)));

struct StepScal {
    float v, uata, m1, m2, m12u, cpLm1, e16, e245, cst2, kq, rdt;
};

// exp(theta) for this workload: theta in (0, ~0.007) -> 4-term Taylor is
// sub-ULP exact (theta^4/24 < 1e-10). Guarded fallback keeps generality.
__device__ __forceinline__ float exp_small(float x)
{
    if (__builtin_expect(fabsf(x) < 0.008f, 1)) {
        float x2 = x * x;
        return 1.0f + x + x2 * 0.5f + x2 * x * (1.0f / 6.0f);
    }
    return expf(x);
}

__device__ __forceinline__ StepScal make_scal(
    float v, float ii, float ta, float f1, float f2_, float f3,
    float kq, float rdt)
{
    const float UA_CP = 100.0f / 4186.0f;
    StepScal sc;
    sc.v  = v;
    sc.m1 = f1 * (1.0f/60.0f);                 // F1*rho/c1 == F1*rho/60000
    sc.m2 = (1.0f - v) * f2_ * (1.0f/60.0f);
    sc.m12u = sc.m1 + sc.m2 + UA_CP;           // folded tank diagonal
    sc.uata = UA_CP * ta;                      // folded ambient leak term
    sc.cpLm1 = 41.86f * sc.m1;                 // (c_p/L_eq)*m1
    float a_ = f2_ * (4186.0f/60.0f);          // m3*c_p
    float b_ = f3 * (1025.0f*4000.0f/60000.0f);// m4*c_p_sw
    float inv_ab = 1.0f / (a_ * b_);
    float rc    = a_ * a_ * inv_ab;            // m3*c_p/(m4*c_p_sw)
    float theta = 10.0f * (b_ - a_) * inv_ab;  // aA=alpha_he*A_he=10
    float e = exp_small(theta);
    float eta1 = (1.0f - e) / (1.1f - rc * e);
    sc.e16  = 1.6f  * eta1;
    sc.e245 = 0.45f * rc;                      // eta2 = rc
    sc.cst2 = 0.5f * ii + 0.04f * ta;          // beta*I + (H/L_eq)*Ta
    sc.kq = kq;
    sc.rdt = rdt;
    return sc;
}

// One simulation step on reduced state s = (T2,T3,T4,T6,T8), T1==T4.
// OFF=true: full affine step; OFF=false: linear part only (basis columns).
template<bool OFF, bool EMIT>
__device__ __forceinline__ void smd_step(float s[5], const StepScal& sc, float* o)
{
    float t2 = s[0], t3 = s[1], t4 = s[2], t6 = s[3], t8 = s[4];

    float lin = -0.04f * (0.5f * (t4 + t2)) - sc.cpLm1 * (t2 - t4);
    if (OFF) lin += sc.cst2;
    float t2n = fmaf(sc.kq, lin, t2);

    float c3 = fmaf(sc.m2, t4, sc.m1 * t2n) - sc.m12u * t3;
    float c4 = fmaf(sc.m2, t6, sc.m1 * t3 ) - sc.m12u * t4;
    if (OFF) { c3 += sc.uata; c4 += sc.uata; }
    float t3n = fmaf(sc.rdt, c3, t3);
    float t4n = fmaf(sc.rdt, c4, t4);

    float t5 = fmaf(sc.v, t6 - t3n, t3n);
    float t7 = OFF ? (t8 - 4.0f) : t8;
    float t6n = fmaf(-sc.e16, t5 - t7, t5);
    float t8n = fmaf(sc.e245, t5 - t6n, t7);

    s[0] = t2n; s[1] = t3n; s[2] = t4n; s[3] = t6n; s[4] = t8n;
    if (EMIT) {
        o[0] = t2n; o[1] = t3n; o[2] = t4n; o[3] = t5;
        o[4] = t6n; o[5] = t7;  o[6] = t8n;
    }
}

// LDS-staged with async-STAGE split: wave w stages step w of each array
// (f4 loads, 1 KB/wave-instr); next group's loads issue before compute.
__global__ __launch_bounds__(256) void phaseA(
    const float* __restrict__ V, const float* __restrict__ I,
    const float* __restrict__ Ta, const float* __restrict__ F1,
    const float* __restrict__ F2, const float* __restrict__ F3,
    const int* __restrict__ dtp, float* __restrict__ maps)
{
    __shared__ float lds[6 * GSTEP * 256];   // 24 KB
    const int t  = threadIdx.x;
    const int b0 = blockIdx.x * 256;
    const int b  = b0 + t;
    const int c  = blockIdx.y;
    const float dtf = (float)dtp[0];
    const float kq  = dtf * (1.0f / 2.093e9f);   // dt/(A_sf*rho*c_p)
    const float rdt = dtf * 1e-4f;               // dt/(rho*TV)

    const int i4 = t >> 6;          // step-within-group this thread stages
    const int m4 = (t & 63) << 2;   // col offset it stages (f4)

    float s[6][5];
#pragma unroll
    for (int j = 0; j < 6; ++j)
#pragma unroll
        for (int i = 0; i < 5; ++i) s[j][i] = (i == j) ? 1.0f : 0.0f;

    const int chunk0 = c * CLEN * BATCH + b0;
    const int NG = CLEN / GSTEP;

    // prologue: issue group-0 loads
    int gb = chunk0 + i4 * BATCH + m4;
    f4 ra = *(const f4*)&V [gb];
    f4 rb = *(const f4*)&I [gb];
    f4 rc = *(const f4*)&Ta[gb];
    f4 rd = *(const f4*)&F1[gb];
    f4 re = *(const f4*)&F2[gb];
    f4 rf = *(const f4*)&F3[gb];

    for (int g = 0; g < NG; ++g) {
        __syncthreads();   // all waves done reading buf (no-op at g=0)
        *(f4*)&lds[(0 * GSTEP + i4) * 256 + m4] = ra;   // vmcnt wait here
        *(f4*)&lds[(1 * GSTEP + i4) * 256 + m4] = rb;
        *(f4*)&lds[(2 * GSTEP + i4) * 256 + m4] = rc;
        *(f4*)&lds[(3 * GSTEP + i4) * 256 + m4] = rd;
        *(f4*)&lds[(4 * GSTEP + i4) * 256 + m4] = re;
        *(f4*)&lds[(5 * GSTEP + i4) * 256 + m4] = rf;
        __syncthreads();   // buf ready
        if (g + 1 < NG) {  // issue NEXT group's loads before compute (T14)
            const int nb = chunk0 + ((g + 1) * GSTEP + i4) * BATCH + m4;
            ra = *(const f4*)&V [nb];
            rb = *(const f4*)&I [nb];
            rc = *(const f4*)&Ta[nb];
            rd = *(const f4*)&F1[nb];
            re = *(const f4*)&F2[nb];
            rf = *(const f4*)&F3[nb];
        }
#pragma unroll
        for (int k = 0; k < GSTEP; ++k) {
            StepScal sc = make_scal(lds[(0 * GSTEP + k) * 256 + t],
                                    lds[(1 * GSTEP + k) * 256 + t],
                                    lds[(2 * GSTEP + k) * 256 + t],
                                    lds[(3 * GSTEP + k) * 256 + t],
                                    lds[(4 * GSTEP + k) * 256 + t],
                                    lds[(5 * GSTEP + k) * 256 + t], kq, rdt);
#pragma unroll
            for (int j = 0; j < 5; ++j) smd_step<false, false>(s[j], sc, nullptr);
            smd_step<true, false>(s[5], sc, nullptr);
        }
    }

    float tmp[32];
#pragma unroll
    for (int j = 0; j < 6; ++j)
#pragma unroll
        for (int i = 0; i < 5; ++i) tmp[j * 5 + i] = s[j][i];
    tmp[30] = 0.0f; tmp[31] = 0.0f;
    // maps layout [b][c][32] contiguous; regular cached stores.
    f4* mp = (f4*)(maps + ((size_t)b * NCHUNK + c) * 32);
#pragma unroll
    for (int k = 0; k < 8; ++k) mp[k] = ((const f4*)tmp)[k];
}

// One block (NCHUNK thr) per batch element; thread c = chunk c.
// Hillis-Steele inclusive scan of affine maps; exclusive prefix -> start state.
__global__ __launch_bounds__(NCHUNK) void phaseB(
    const float* __restrict__ maps, float* __restrict__ states)
{
    __shared__ float lds[NCHUNK * 33];
    const int b = blockIdx.x;
    const int c = threadIdx.x;

    float tmp[32];
    const f4* mp = (const f4*)(maps + ((size_t)b * NCHUNK + c) * 32);
#pragma unroll
    for (int k = 0; k < 8; ++k) ((f4*)tmp)[k] = mp[k];
    float m[30];
#pragma unroll
    for (int k = 0; k < 30; ++k) m[k] = tmp[k];

#pragma unroll
    for (int d = 1; d < NCHUNK; d <<= 1) {
#pragma unroll
        for (int k = 0; k < 30; ++k) lds[c * 33 + k] = m[k];
        __syncthreads();
        float o[30];
        const bool act = (c >= d);
        if (act) {
#pragma unroll
            for (int k = 0; k < 30; ++k) o[k] = lds[(c - d) * 33 + k];
        }
        __syncthreads();
        if (act) {
            // compose: result = mine ∘ other (other applied first)
            float nm[30];
#pragma unroll
            for (int j = 0; j < 5; ++j)
#pragma unroll
                for (int i = 0; i < 5; ++i) {
                    float acc = m[0 * 5 + i] * o[j * 5 + 0];
#pragma unroll
                    for (int k = 1; k < 5; ++k)
                        acc = fmaf(m[k * 5 + i], o[j * 5 + k], acc);
                    nm[j * 5 + i] = acc;
                }
#pragma unroll
            for (int i = 0; i < 5; ++i) {
                float acc = m[25 + i];
#pragma unroll
                for (int k = 0; k < 5; ++k)
                    acc = fmaf(m[k * 5 + i], o[25 + k], acc);
                nm[25 + i] = acc;
            }
#pragma unroll
            for (int k = 0; k < 30; ++k) m[k] = nm[k];
        }
    }

    // exclusive prefix -> chunk-start state
#pragma unroll
    for (int k = 0; k < 30; ++k) lds[c * 33 + k] = m[k];
    __syncthreads();

    const float s0[5] = {60.0f, 60.0f, 50.0f, 25.0f, 60.0f};
    float st[8];
#pragma unroll
    for (int i = 0; i < 5; ++i) st[i] = s0[i];
    st[5] = 0.0f; st[6] = 0.0f; st[7] = 0.0f;
    if (c > 0) {
        const float* pm = &lds[(c - 1) * 33];
#pragma unroll
        for (int i = 0; i < 5; ++i) {
            float acc = pm[25 + i];
#pragma unroll
            for (int j = 0; j < 5; ++j)
                acc = fmaf(pm[j * 5 + i], s0[j], acc);
            st[i] = acc;
        }
    }
    // states layout [c][b][8]; regular cached stores (phase C re-reads these).
    f4* op = (f4*)(states + ((size_t)c * BATCH + b) * 8);
    op[0] = ((const f4*)st)[0];
    op[1] = ((const f4*)st)[1];
}

// Two adjacent batch columns per thread: all global traffic is dwordx2.
// (Safe here: only 5 live state floats per column.)
__global__ __launch_bounds__(256, 4) void phaseC(
    const float* __restrict__ V, const float* __restrict__ I,
    const float* __restrict__ Ta, const float* __restrict__ F1,
    const float* __restrict__ F2, const float* __restrict__ F3,
    const int* __restrict__ dtp, const float* __restrict__ states,
    float* __restrict__ out)
{
    const int pair = blockIdx.x * blockDim.x + threadIdx.x;
    const int b = pair * 2;
    const int c = blockIdx.y;
    const float dtf = (float)dtp[0];
    const float kq  = dtf * (1.0f / 2.093e9f);
    const float rdt = dtf * 1e-4f;

    // states for b and b+1 are 64 contiguous bytes: 4x f4.
    const f4* sp4 = (const f4*)(states + ((size_t)c * BATCH + b) * 8);
    f4 q0 = sp4[0], q1 = sp4[1], q2 = sp4[2], q3 = sp4[3];
    float s0v[5] = {q0.x, q0.y, q0.z, q0.w, q1.x};
    float s1v[5] = {q2.x, q2.y, q2.z, q2.w, q3.x};

    int idx = c * CLEN * BATCH + b;
#pragma unroll 4
    for (int k = 0; k < CLEN; ++k, idx += BATCH) {
        f2 v2  = *(const f2*)&V[idx];
        f2 i2  = *(const f2*)&I[idx];
        f2 ta2 = *(const f2*)&Ta[idx];
        f2 f12 = *(const f2*)&F1[idx];
        f2 f22 = *(const f2*)&F2[idx];
        f2 f32 = *(const f2*)&F3[idx];
        StepScal sca = make_scal(v2.x, i2.x, ta2.x, f12.x, f22.x, f32.x, kq, rdt);
        StepScal scb = make_scal(v2.y, i2.y, ta2.y, f12.y, f22.y, f32.y, kq, rdt);
        float oa[7], ob[7];
        smd_step<true, true>(s0v, sca, oa);
        smd_step<true, true>(s1v, scb, ob);
#pragma unroll
        for (int q = 0; q < 7; ++q) {
            f2 w; w.x = oa[q]; w.y = ob[q];
            __builtin_nontemporal_store(w, (f2*)&out[q * (T_STEPS * BATCH) + idx]);
        }
    }
}

// Fallback if d_ws is too small: plain serial per batch.
__global__ __launch_bounds__(256) void serialK(
    const float* __restrict__ V, const float* __restrict__ I,
    const float* __restrict__ Ta, const float* __restrict__ F1,
    const float* __restrict__ F2, const float* __restrict__ F3,
    const int* __restrict__ dtp, float* __restrict__ out)
{
    const int b = blockIdx.x * blockDim.x + threadIdx.x;
    const float dtf = (float)dtp[0];
    const float kq  = dtf * (1.0f / 2.093e9f);
    const float rdt = dtf * 1e-4f;
    float s[5] = {60.0f, 60.0f, 50.0f, 25.0f, 60.0f};
    int idx = b;
    for (int t = 0; t < T_STEPS; ++t, idx += BATCH) {
        StepScal sc = make_scal(V[idx], I[idx], Ta[idx], F1[idx], F2[idx], F3[idx], kq, rdt);
        float o[7];
        smd_step<true, true>(s, sc, o);
#pragma unroll
        for (int q = 0; q < 7; ++q)
            __builtin_nontemporal_store(o[q], &out[q * (T_STEPS * BATCH) + idx]);
    }
}

extern "C" void kernel_launch(void* const* d_in, const int* in_sizes, int n_in,
                              void* d_out, int out_size, void* d_ws, size_t ws_size,
                              hipStream_t stream)
{
    const float* V  = (const float*)d_in[0];
    const float* I  = (const float*)d_in[1];
    const float* Ta = (const float*)d_in[2];
    const float* F1 = (const float*)d_in[3];
    const float* F2 = (const float*)d_in[4];
    const float* F3 = (const float*)d_in[5];
    const int*  dtp = (const int*)d_in[6];
    float* out = (float*)d_out;

    const size_t need = ((size_t)NCHUNK * BATCH * 32 + (size_t)NCHUNK * BATCH * 8) * sizeof(float);
    if (need <= ws_size) {
        float* maps   = (float*)d_ws;                           // BATCH*NCHUNK*32 floats
        float* states = maps + (size_t)BATCH * NCHUNK * 32;     // NCHUNK*BATCH*8 floats
        hipLaunchKernelGGL(phaseA, dim3(BATCH / 256, NCHUNK), dim3(256), 0, stream,
                           V, I, Ta, F1, F2, F3, dtp, maps);
        hipLaunchKernelGGL(phaseB, dim3(BATCH), dim3(NCHUNK), 0, stream,
                           maps, states);
        hipLaunchKernelGGL(phaseC, dim3(BATCH / 512, NCHUNK), dim3(256), 0, stream,
                           V, I, Ta, F1, F2, F3, dtp, states, out);
    } else {
        hipLaunchKernelGGL(serialK, dim3(BATCH / 256), dim3(256), 0, stream,
                           V, I, Ta, F1, F2, F3, dtp, out);
    }
}